// Round 2
// baseline (445.391 us; speedup 1.0000x reference)
//
#include <hip/hip_runtime.h>

typedef _Float16 half8 __attribute__((ext_vector_type(8)));
typedef _Float16 half4v __attribute__((ext_vector_type(4)));
typedef float f32x4 __attribute__((ext_vector_type(4)));

__device__ __forceinline__ void gld_lds16(const void* g, void* l) {
  __builtin_amdgcn_global_load_lds((const __attribute__((address_space(1))) void*)g,
                                   (__attribute__((address_space(3))) void*)l, 16, 0, 0);
}

// ---------------- fp32 -> f16 convert (vectorized) ----------------
__global__ void cvt_f32_f16(const float* __restrict__ src, _Float16* __restrict__ dst, int n4) {
  int i = blockIdx.x * 256 + threadIdx.x;
  if (i < n4) {
    float4 v = ((const float4*)src)[i];
    half4v h;
    h.x = (_Float16)v.x; h.y = (_Float16)v.y; h.z = (_Float16)v.z; h.w = (_Float16)v.w;
    ((half4v*)dst)[i] = h;
  }
}

// ---------------- mask tile flags: flag=1 iff no zeros in 128x64 tile ----------------
__global__ void mask_flags_k(const int* __restrict__ mask, unsigned char* __restrict__ flags) {
  int qt = blockIdx.x, kt = blockIdx.y; // 16 x 32
  __shared__ int allv;
  if (threadIdx.x == 0) allv = 1;
  __syncthreads();
  int ok = 1;
  for (int idx = threadIdx.x; idx < 128 * 64; idx += 256) {
    int qr = qt * 128 + (idx >> 6);
    int kc = kt * 64 + (idx & 63);
    ok &= (mask[(size_t)qr * 2048 + kc] != 0);
  }
  if (!ok) atomicAnd(&allv, 0);
  __syncthreads();
  if (threadIdx.x == 0) flags[qt * 32 + kt] = (unsigned char)allv;
}

// ---------------- GEMM: y[M=8192,N=1024] = A[M,1024] @ B[N,1024]^T + bias ----------------
// LAYOUT 0: f16 heads [b,h,s,d]   LAYOUT 1: f16 V^T [b,h,d,s]   LAYOUT 2: fp32 [row,col]
template <int LAYOUT>
__global__ __launch_bounds__(256, 2) void gemm_k(const _Float16* __restrict__ A,
                                                 const _Float16* __restrict__ B,
                                                 const float* __restrict__ bias,
                                                 void* __restrict__ dst) {
  __shared__ _Float16 Alds[128][32];
  __shared__ _Float16 Blds[128][32];
  int tid = threadIdx.x, w = tid >> 6, l = tid & 63;
  int lm = l & 15, lg = l >> 4;
  int wm = w >> 1, wn = w & 1;
  int m0 = blockIdx.y * 128, n0 = blockIdx.x * 128;
  f32x4 acc[4][4] = {};
  for (int k0 = 0; k0 < 1024; k0 += 32) {
#pragma unroll
    for (int c = 0; c < 2; ++c) {
      int o = w * 2048 + c * 1024 + l * 16;  // byte offset within 8KB tile
      int row = o >> 6;
      int kb = (o & 63) >> 1;  // f16 element offset within row
      gld_lds16(A + (size_t)(m0 + row) * 1024 + k0 + kb, (char*)&Alds[0][0] + w * 2048 + c * 1024);
      gld_lds16(B + (size_t)(n0 + row) * 1024 + k0 + kb, (char*)&Blds[0][0] + w * 2048 + c * 1024);
    }
    __syncthreads();
    half8 af[4], bf[4];
#pragma unroll
    for (int m = 0; m < 4; ++m) af[m] = *(const half8*)&Alds[wm * 64 + m * 16 + lm][lg * 8];
#pragma unroll
    for (int n = 0; n < 4; ++n) bf[n] = *(const half8*)&Blds[wn * 64 + n * 16 + lm][lg * 8];
#pragma unroll
    for (int m = 0; m < 4; ++m)
#pragma unroll
      for (int n = 0; n < 4; ++n)
        acc[m][n] = __builtin_amdgcn_mfma_f32_16x16x32_f16(af[m], bf[n], acc[m][n], 0, 0, 0);
    __syncthreads();
  }
  float bs[4];
#pragma unroll
  for (int n = 0; n < 4; ++n) bs[n] = bias[n0 + wn * 64 + n * 16 + lm];
#pragma unroll
  for (int m = 0; m < 4; ++m) {
#pragma unroll
    for (int n = 0; n < 4; ++n) {
      int colg = n0 + wn * 64 + n * 16 + lm;
#pragma unroll
      for (int j = 0; j < 4; ++j) {
        int rowg = m0 + wm * 64 + m * 16 + lg * 4 + j;
        float v = acc[m][n][j] + bs[n];
        if constexpr (LAYOUT == 0) {
          int b = rowg >> 11, s = rowg & 2047, h = colg >> 6, d = colg & 63;
          ((_Float16*)dst)[((size_t)(b * 16 + h) * 2048 + s) * 64 + d] = (_Float16)v;
        } else if constexpr (LAYOUT == 1) {
          int b = rowg >> 11, s = rowg & 2047, h = colg >> 6, d = colg & 63;
          ((_Float16*)dst)[((size_t)(b * 16 + h) * 64 + d) * 2048 + s] = (_Float16)v;
        } else {
          ((float*)dst)[(size_t)rowg * 1024 + colg] = v;
        }
      }
    }
  }
}

// ---------------- flash attention ----------------
// grid (16 qtiles, 64 bh), 256 threads = 4 waves; wave w owns 32 q-rows.
__global__ __launch_bounds__(256, 2) void attn_k(const _Float16* __restrict__ Q,
                                                 const _Float16* __restrict__ K,
                                                 const _Float16* __restrict__ Vt,
                                                 const unsigned char* __restrict__ flags,
                                                 const int* __restrict__ mask,
                                                 _Float16* __restrict__ out) {
  __shared__ __align__(16) char Plds[4][4096];  // per-wave 32 rows x 128B, XOR-swizzled
  int qt = blockIdx.x, bh = blockIdx.y;
  int tid = threadIdx.x, w = tid >> 6, l = tid & 63;
  int lm = l & 15, lg = l >> 4;
  const size_t hb = (size_t)bh * (2048 * 64);
  int q0 = qt * 128 + w * 32;
  const float L2E = 1.4426950408889634f;

  half8 qf[2][2];
#pragma unroll
  for (int m = 0; m < 2; ++m)
#pragma unroll
    for (int kk = 0; kk < 2; ++kk) {
      half8 q = *(const half8*)&Q[hb + (size_t)(q0 + m * 16 + lm) * 64 + kk * 32 + lg * 8];
#pragma unroll
      for (int i = 0; i < 8; ++i) q[i] = q[i] * (_Float16)0.125f;  // 1/sqrt(64), exact
      qf[m][kk] = q;
    }

  f32x4 oacc[2][4] = {};
  f32x4 mrun[2], lrun[2];
#pragma unroll
  for (int m = 0; m < 2; ++m) {
    mrun[m] = f32x4{-1e30f, -1e30f, -1e30f, -1e30f};
    lrun[m] = f32x4{0.f, 0.f, 0.f, 0.f};
  }

  for (int t = 0; t < 32; ++t) {
    int flg = flags[qt * 32 + t];
    half8 kf[4][2];
#pragma unroll
    for (int n = 0; n < 4; ++n)
#pragma unroll
      for (int kk = 0; kk < 2; ++kk)
        kf[n][kk] = *(const half8*)&K[hb + (size_t)(t * 64 + n * 16 + lm) * 64 + kk * 32 + lg * 8];
    f32x4 s[2][4];
    f32x4 z = {0.f, 0.f, 0.f, 0.f};
#pragma unroll
    for (int m = 0; m < 2; ++m)
#pragma unroll
      for (int n = 0; n < 4; ++n) {
        s[m][n] = __builtin_amdgcn_mfma_f32_16x16x32_f16(qf[m][0], kf[n][0], z, 0, 0, 0);
        s[m][n] = __builtin_amdgcn_mfma_f32_16x16x32_f16(qf[m][1], kf[n][1], s[m][n], 0, 0, 0);
      }
    if (!flg) {  // slow path: per-element mask (not taken for all-ones mask)
#pragma unroll
      for (int m = 0; m < 2; ++m)
#pragma unroll
        for (int n = 0; n < 4; ++n)
#pragma unroll
          for (int j = 0; j < 4; ++j) {
            int qr = qt * 128 + w * 32 + m * 16 + lg * 4 + j;
            int kc = t * 64 + n * 16 + lm;
            if (mask[(size_t)qr * 2048 + kc] == 0) s[m][n][j] = -1e30f;
          }
    }
#pragma unroll
    for (int m = 0; m < 2; ++m) {
      f32x4 pm = s[m][0];
#pragma unroll
      for (int n = 1; n < 4; ++n)
#pragma unroll
        for (int j = 0; j < 4; ++j) pm[j] = fmaxf(pm[j], s[m][n][j]);
#pragma unroll
      for (int msk = 1; msk < 16; msk <<= 1)
#pragma unroll
        for (int j = 0; j < 4; ++j) pm[j] = fmaxf(pm[j], __shfl_xor(pm[j], msk, 64));
      f32x4 mnew, alpha, psum;
#pragma unroll
      for (int j = 0; j < 4; ++j) {
        mnew[j] = fmaxf(mrun[m][j], pm[j]);
        alpha[j] = exp2f((mrun[m][j] - mnew[j]) * L2E);
        psum[j] = 0.f;
      }
#pragma unroll
      for (int n = 0; n < 4; ++n)
#pragma unroll
        for (int j = 0; j < 4; ++j) {
          float p = exp2f((s[m][n][j] - mnew[j]) * L2E);
          s[m][n][j] = p;
          psum[j] += p;
        }
      // BUGFIX (round 2): reduce the row-sum across the 16 lanes sharing each
      // row (lm bits 0-3) — previously psum held only this lane's 4 columns,
      // so lrun was ~1/16 of the true denominator (observed 5.1 absmax ~ 14x).
#pragma unroll
      for (int msk = 1; msk < 16; msk <<= 1)
#pragma unroll
        for (int j = 0; j < 4; ++j) psum[j] += __shfl_xor(psum[j], msk, 64);
#pragma unroll
      for (int j = 0; j < 4; ++j) {
        lrun[m][j] = lrun[m][j] * alpha[j] + psum[j];
        mrun[m][j] = mnew[j];
      }
#pragma unroll
      for (int n = 0; n < 4; ++n)
#pragma unroll
        for (int j = 0; j < 4; ++j) oacc[m][n][j] *= alpha[j];
      // write P to per-wave swizzled LDS (row stride 128B -> XOR swizzle, G4)
#pragma unroll
      for (int n = 0; n < 4; ++n)
#pragma unroll
        for (int j = 0; j < 4; ++j) {
          int row = m * 16 + lg * 4 + j;
          int byte = row * 128 + (((n * 16 + lm) * 2) ^ ((row & 7) << 4));
          *(_Float16*)(&Plds[w][byte]) = (_Float16)s[m][n][j];
        }
    }
    // read P as A-fragments (same swizzle), load V^T fragments, PV MFMA
    half8 pa[2][2];
#pragma unroll
    for (int m = 0; m < 2; ++m)
#pragma unroll
      for (int ks = 0; ks < 2; ++ks) {
        int row = m * 16 + lm;
        int byte = row * 128 + ((ks * 64 + lg * 16) ^ ((row & 7) << 4));
        pa[m][ks] = *(const half8*)(&Plds[w][byte]);
      }
    half8 vf[4][2];
#pragma unroll
    for (int n = 0; n < 4; ++n)
#pragma unroll
      for (int ks = 0; ks < 2; ++ks)
        vf[n][ks] = *(const half8*)&Vt[hb + (size_t)(n * 16 + lm) * 2048 + t * 64 + ks * 32 + lg * 8];
#pragma unroll
    for (int m = 0; m < 2; ++m)
#pragma unroll
      for (int n = 0; n < 4; ++n) {
        oacc[m][n] = __builtin_amdgcn_mfma_f32_16x16x32_f16(pa[m][0], vf[n][0], oacc[m][n], 0, 0, 0);
        oacc[m][n] = __builtin_amdgcn_mfma_f32_16x16x32_f16(pa[m][1], vf[n][1], oacc[m][n], 0, 0, 0);
      }
  }
  int b = bh >> 4, h = bh & 15;
#pragma unroll
  for (int m = 0; m < 2; ++m)
#pragma unroll
    for (int n = 0; n < 4; ++n)
#pragma unroll
      for (int j = 0; j < 4; ++j) {
        float v = oacc[m][n][j] / lrun[m][j];
        int sg = q0 + m * 16 + lg * 4 + j;
        int col = h * 64 + n * 16 + lm;
        out[((size_t)(b * 2048 + sg)) * 1024 + col] = (_Float16)v;
      }
}

extern "C" void kernel_launch(void* const* d_in, const int* in_sizes, int n_in,
                              void* d_out, int out_size, void* d_ws, size_t ws_size,
                              hipStream_t stream) {
  const float* x = (const float*)d_in[0];
  const int* mask = (const int*)d_in[1];
  const float* Wq = (const float*)d_in[2];
  const float* bq = (const float*)d_in[3];
  const float* Wk = (const float*)d_in[4];
  const float* bk = (const float*)d_in[5];
  const float* Wv = (const float*)d_in[6];
  const float* bv = (const float*)d_in[7];
  const float* Wo = (const float*)d_in[8];
  const float* bo = (const float*)d_in[9];

  char* ws = (char*)d_ws;
  _Float16* xh = (_Float16*)(ws);                       // 16 MB, later reused as attn out
  _Float16* Wqh = (_Float16*)(ws + (16ull << 20));      // 2 MB
  _Float16* Wkh = (_Float16*)(ws + (18ull << 20));      // 2 MB
  _Float16* Wvh = (_Float16*)(ws + (20ull << 20));      // 2 MB
  _Float16* Woh = (_Float16*)(ws + (22ull << 20));      // 2 MB
  _Float16* Vt = (_Float16*)(ws + (24ull << 20));       // 16 MB
  unsigned char* flags = (unsigned char*)(ws + (40ull << 20));  // 512 B
  // Q and K scratch live inside d_out (32 MB fp32), fully overwritten by final GEMM
  _Float16* Qw = (_Float16*)d_out;
  _Float16* Kw = (_Float16*)((char*)d_out + (16ull << 20));
  _Float16* Ah = xh;  // attention output reuses x-f16 region

  cvt_f32_f16<<<8192, 256, 0, stream>>>(x, xh, 2097152);
  cvt_f32_f16<<<1024, 256, 0, stream>>>(Wq, Wqh, 262144);
  cvt_f32_f16<<<1024, 256, 0, stream>>>(Wk, Wkh, 262144);
  cvt_f32_f16<<<1024, 256, 0, stream>>>(Wv, Wvh, 262144);
  cvt_f32_f16<<<1024, 256, 0, stream>>>(Wo, Woh, 262144);
  mask_flags_k<<<dim3(16, 32), 256, 0, stream>>>(mask, flags);
  gemm_k<0><<<dim3(8, 64), 256, 0, stream>>>(xh, Wqh, bq, Qw);
  gemm_k<0><<<dim3(8, 64), 256, 0, stream>>>(xh, Wkh, bk, Kw);
  gemm_k<1><<<dim3(8, 64), 256, 0, stream>>>(xh, Wvh, bv, Vt);
  attn_k<<<dim3(16, 64), 256, 0, stream>>>(Qw, Kw, Vt, flags, mask, Ah);
  gemm_k<2><<<dim3(8, 64), 256, 0, stream>>>(Ah, Woh, bo, d_out);
}